// Round 14
// baseline (146.824 us; speedup 1.0000x reference)
//
#include <hip/hip_runtime.h>
#include <hip/hip_bf16.h>

typedef unsigned short u16;
typedef unsigned int u32;
typedef __attribute__((ext_vector_type(8))) short short8;
typedef __attribute__((ext_vector_type(4))) float floatx4;
typedef __attribute__((ext_vector_type(4))) u32 u32x4;

#define NU 16384
#define DIM 256
#define AMS 200               // Am / Ac1 LDS row stride (u16)
#define AC1o 12800u           // Ac1 (same-mask image) offset in U (64*200)
#define YLO 16896u            // Y lo half offset (hi at 0)
#define STGo 33792u           // ph1 staging dbuf (2 x 6144 floats), u16 offset

// ws layout (u16 offsets) — XH/XL/XR retired (kernels read fp32 x directly)
#define ST0 20971520u
#define STROW 16512u          // 64 guard + 16384 + 64 guard
#define STMAT 4227072u        // 256 * STROW
#define WH0o 33652736u        // ST0 + 3*STMAT
#define WL0o 33718272u
#define WRo  33783808u        // 3 mats x 65536

__device__ __forceinline__ u16 bfh(float v) {            // truncate to bf16
  return (u16)(__float_as_uint(v) >> 16);
}
__device__ __forceinline__ float bup(u16 u) {
  return __uint_as_float(((u32)u) << 16);
}
__device__ __forceinline__ u16 bfrn(float v) {           // round-nearest-even
  u32 u = __float_as_uint(v);
  return (u16)((u + 0x7fffu + ((u >> 16) & 1u)) >> 16);
}

// split 8 fp32 -> bf16 hi/lo fragments (bit-identical to prep's bfh/bup path)
__device__ __forceinline__ void cvt8(float4 a, float4 b, short8& hi, short8& lo) {
  float f[8] = {a.x, a.y, a.z, a.w, b.x, b.y, b.z, b.w};
  u32 hw[4], lw[4];
#pragma unroll
  for (int i = 0; i < 4; ++i) {
    u32 u0 = __float_as_uint(f[2 * i]);
    u32 u1 = __float_as_uint(f[2 * i + 1]);
    hw[i] = (u1 & 0xFFFF0000u) | (u0 >> 16);
    float r0 = f[2 * i]     - __uint_as_float(u0 & 0xFFFF0000u);
    float r1 = f[2 * i + 1] - __uint_as_float(u1 & 0xFFFF0000u);
    lw[i] = (__float_as_uint(r1) & 0xFFFF0000u) | (__float_as_uint(r0) >> 16);
  }
  u32x4 h = {hw[0], hw[1], hw[2], hw[3]};
  u32x4 l = {lw[0], lw[1], lw[2], lw[3]};
  hi = __builtin_bit_cast(short8, h);
  lo = __builtin_bit_cast(short8, l);
}

// async global->LDS 16B (linear wave dest: base + lane*16)
__device__ __forceinline__ void gload16(const u16* g, u16* l) {
  __builtin_amdgcn_global_load_lds(
      (__attribute__((address_space(1))) void*)(uintptr_t)g,
      (__attribute__((address_space(3))) void*)(uintptr_t)l, 16, 0, 0);
}

// ---------------------------------------------------------------------------
// prep: W imaging (32 blocks) + S^T guard zeroing (96 blocks). x-imaging
// retired — gemmS1/fused_attn convert from fp32 x inline.
// ---------------------------------------------------------------------------
__global__ __launch_bounds__(256) void prep(
    const float* __restrict__ wat, const float* __restrict__ wpr,
    const float* __restrict__ wsu, const float* __restrict__ wsm,
    const float* __restrict__ wdf, u16* __restrict__ ws) {
  const int b = blockIdx.x, t = threadIdx.x;
  if (b < 32) {
    const int s = b & 7, mat = b >> 3, n = t;
    const float* Wa = (mat == 0) ? wat : (mat == 1) ? wpr : (mat == 2) ? wsm : wsu;
    const float* Wb = (mat == 0) ? wat : (mat == 1) ? wsu : (mat == 2) ? wdf : wdf;
    const float c1  = (mat == 0) ? 0.f : (mat == 3) ? 1.f : -1.f;
    u16 hbuf[32], lbuf[32];
#pragma unroll 8
    for (int k = 0; k < 32; ++k) {
      float v = Wa[(s * 32 + k) * 256 + n] + c1 * Wb[(s * 32 + k) * 256 + n];
      if (mat == 0) { hbuf[k] = bfh(v); lbuf[k] = bfh(v - bup(hbuf[k])); }
      else          { hbuf[k] = bfrn(v); }
    }
    u16* dh = ws + ((mat == 0) ? WH0o : (WRo + (size_t)(mat - 1) * 65536))
               + (size_t)s * 8192 + n * 32;
#pragma unroll
    for (int p = 0; p < 4; ++p) *(uint4*)(dh + p * 8) = ((const uint4*)hbuf)[p];
    if (mat == 0) {
      u16* dl = ws + WL0o + (size_t)s * 8192 + n * 32;
#pragma unroll
      for (int p = 0; p < 4; ++p) *(uint4*)(dl + p * 8) = ((const uint4*)lbuf)[p];
    }
  } else {
    int g = (b - 32) * 256 + t;                    // 24576 threads
    int r = g >> 13, rem = g & 8191;
    int d = rem >> 5, p = rem & 31;
    size_t base = ST0 + (size_t)r * STMAT + (size_t)d * STROW;
    size_t off = (p < 16) ? (base + p * 4) : (base + 16448 + (p - 16) * 4);
    *(ushort4*)(ws + off) = make_ushort4(0, 0, 0, 0);
  }
}

// ---------------------------------------------------------------------------
// gemmS1: S1..S3 -> S^T (A-strip converted inline from fp32 x — round-8
// proven, bit-identical to the retired XR image).
// ---------------------------------------------------------------------------
__global__ __launch_bounds__(512, 4) void gemmS1(const float* __restrict__ x,
                                                 u16* __restrict__ ws) {
  __shared__ __align__(16) u16 U[39168];   // Ar[32*264] @0 ; Ct[3][10240] @8448

  const int t = threadIdx.x, row0 = blockIdx.x * 32;
  const int w = t >> 6, ln = t & 15, quad = (t & 63) >> 4, q8 = quad * 8;
  const int n0 = w * 32;

#pragma unroll
  for (int cc = 0; cc < 4; ++cc) {
    int idx = t + 512 * cc;                  // 0..2047, 4 elems each
    int row = idx >> 6, c4 = (idx & 63) * 4;
    float4 v = *(const float4*)(x + (size_t)(row0 + row) * 256 + c4);
    ushort4 pk = make_ushort4(bfrn(v.x), bfrn(v.y), bfrn(v.z), bfrn(v.w));
    *(ushort4*)(U + row * 264 + c4) = pk;
  }
  __syncthreads();

  floatx4 acc[3][2][2];
#pragma unroll
  for (int mat = 0; mat < 3; ++mat)
#pragma unroll
    for (int m = 0; m < 2; ++m)
#pragma unroll
      for (int nt = 0; nt < 2; ++nt) acc[mat][m][nt] = (floatx4){0.f, 0.f, 0.f, 0.f};

  for (int s = 0; s < 8; ++s) {
    short8 ah[2];
#pragma unroll
    for (int m = 0; m < 2; ++m)
      ah[m] = *(const short8*)(U + (m * 16 + ln) * 264 + s * 32 + q8);
#pragma unroll
    for (int mat = 0; mat < 3; ++mat) {
      short8 bh[2];
#pragma unroll
      for (int nt = 0; nt < 2; ++nt)
        bh[nt] = *(const short8*)(ws + WRo + (size_t)mat * 65536
                                  + (size_t)s * 8192 + (n0 + nt * 16 + ln) * 32 + q8);
#pragma unroll
      for (int m = 0; m < 2; ++m)
#pragma unroll
        for (int nt = 0; nt < 2; ++nt)
          acc[mat][m][nt] = __builtin_amdgcn_mfma_f32_16x16x32_bf16(ah[m], bh[nt], acc[mat][m][nt], 0, 0, 0);
    }
  }

#pragma unroll
  for (int mat = 0; mat < 3; ++mat)
#pragma unroll
    for (int m = 0; m < 2; ++m)
#pragma unroll
      for (int nt = 0; nt < 2; ++nt) {
        int col = n0 + nt * 16 + ln;
        ushort4 pk = make_ushort4(bfrn(acc[mat][m][nt][0]), bfrn(acc[mat][m][nt][1]),
                                  bfrn(acc[mat][m][nt][2]), bfrn(acc[mat][m][nt][3]));
        *(ushort4*)(U + 8448 + mat * 10240 + col * 40 + m * 16 + quad * 4) = pk;
      }
  __syncthreads();

#pragma unroll
  for (int mat = 0; mat < 3; ++mat)
#pragma unroll
    for (int cc = 0; cc < 2; ++cc) {
      int c = t + 512 * cc;                  // 0..1023 : 256 d x 4 parts
      int d = c >> 2, part = c & 3;
      *(uint4*)(ws + ST0 + (size_t)mat * STMAT + (size_t)d * STROW + 64 + row0 + part * 8) =
          *(const uint4*)(U + 8448 + mat * 10240 + d * 40 + part * 8);
    }
}

// ---------------------------------------------------------------------------
// fused_attn v12 = round-7 structure with fp32-direct X (no XH/XL images):
//  Phase A: strip staged as fp32 [64][260], hi/lo split in registers (cvt8).
//  ph1: staged dbuf of fp32 x window [192][32] (same bytes/LDS as old hi+lo),
//       8-chunk source-side swizzle, cvt8 per fragment. Plain __syncthreads.
//  softmax in registers; Am@0 + Ac1@12800 overlay dead Y.
//  ph2: barrier-free band-trick, direct-global S^T B-frags. Unchanged.
// ---------------------------------------------------------------------------
__global__ __launch_bounds__(512) void fused_attn(
    const float* __restrict__ x, const u16* __restrict__ ws,
    const int* __restrict__ spk, float* __restrict__ out)
{
  __shared__ __align__(16) u16 U[58368];   // fp32 strip / Y hi+lo @0; stage@33792; Am/Ac1 after
  __shared__ int spkw[192];
  __shared__ float prt[64][2], prs[64][2];
  __shared__ float red[64][8];

  const int t    = threadIdx.x;
  const int w    = t >> 6;
  const int ln   = t & 15;
  const int quad = (t & 63) >> 4;
  const int q8   = quad * 8;
  // XCD-chunked bijective swizzle (grid 256 % 8 == 0)
  const int bswz = (blockIdx.x & 7) * 32 + (blockIdx.x >> 3);
  const int i0   = bswz * 64;
  const int mw   = w & 3;                      // ph1 m-frag (16 rows)
  const int half = w >> 2;                     // ph1 window col half (96 each)
  const int n0   = w * 32;                     // phase A / ph2 col block

  if (t < 192) spkw[t] = spk[min(max(i0 - 64 + t, 0), NU - 1)];

  // ---------------- Phase A: Y = Xstrip @ W_att (fp32 strip + cvt8) ----------------
  {
    float* Sf = (float*)U;                     // strip fp32 [64][260]
#pragma unroll
    for (int cc = 0; cc < 8; ++cc) {
      int idx = t + 512 * cc;                  // 0..4095
      int row = idx >> 6, c4 = (idx & 63) * 4;
      *(float4*)(Sf + row * 260 + c4) =
          *(const float4*)(x + (size_t)(i0 + row) * 256 + c4);
    }
    __syncthreads();

    floatx4 acc[4][2];
#pragma unroll
    for (int m = 0; m < 4; ++m)
#pragma unroll
      for (int nt = 0; nt < 2; ++nt) acc[m][nt] = (floatx4){0.f, 0.f, 0.f, 0.f};

    for (int s = 0; s < 8; ++s) {
      short8 ah[4], al[4];
#pragma unroll
      for (int m = 0; m < 4; ++m) {
        int base = (m * 16 + ln) * 260 + s * 32 + q8;
        float4 a0 = *(const float4*)(Sf + base);
        float4 a1 = *(const float4*)(Sf + base + 4);
        cvt8(a0, a1, ah[m], al[m]);
      }
      short8 bh[2], bl[2];
#pragma unroll
      for (int nt = 0; nt < 2; ++nt) {
        size_t off = (size_t)s * 8192 + (n0 + nt * 16 + ln) * 32 + q8;
        bh[nt] = *(const short8*)(ws + WH0o + off);
        bl[nt] = *(const short8*)(ws + WL0o + off);
      }
#pragma unroll
      for (int m = 0; m < 4; ++m)
#pragma unroll
        for (int nt = 0; nt < 2; ++nt) {
          acc[m][nt] = __builtin_amdgcn_mfma_f32_16x16x32_bf16(ah[m], bh[nt], acc[m][nt], 0, 0, 0);
          acc[m][nt] = __builtin_amdgcn_mfma_f32_16x16x32_bf16(ah[m], bl[nt], acc[m][nt], 0, 0, 0);
          acc[m][nt] = __builtin_amdgcn_mfma_f32_16x16x32_bf16(al[m], bh[nt], acc[m][nt], 0, 0, 0);
        }
    }
    __syncthreads();                           // strip reads complete

    // write Y hi/lo [64][264] u16 (overlays dead fp32 strip)
#pragma unroll
    for (int m = 0; m < 4; ++m)
#pragma unroll
      for (int nt = 0; nt < 2; ++nt) {
        int col = n0 + nt * 16 + ln;
#pragma unroll
        for (int r = 0; r < 4; ++r) {
          int row = m * 16 + quad * 4 + r;
          float y = acc[m][nt][r];
          u16 hh = bfh(y);
          U[row * 264 + col] = hh;
          U[YLO + row * 264 + col] = bfh(y - bup(hh));
        }
      }
  }

  // ---- ph1 staging: fp32 window [192][32], async 16B, linear LDS dest,
  //      8-chunk source-side swizzle (chunk ^= row&7) ----
  auto STAGE = [&](int ks, int par) {
    const int kd = ks * 32;
    float* db = (float*)(U + STGo) + par * 6144;
#pragma unroll
    for (int cc = 0; cc < 3; ++cc) {
      int e   = t + 512 * cc;                  // 0..1535
      int row = e >> 3, pos = e & 7;
      int sw  = pos ^ (row & 7);
      int jc  = min(max(i0 + row - 64, 0), NU - 1);
      gload16((const u16*)(x + (size_t)jc * 256 + kd + sw * 4),
              (u16*)(db + e * 4));
    }
  };

  // ---------------- Phase 1: P = Y . Xwin^T ----------------
  floatx4 accP[6];
#pragma unroll
  for (int cc = 0; cc < 6; ++cc) accP[cc] = (floatx4){0.f, 0.f, 0.f, 0.f};

  STAGE(0, 0);
  __syncthreads();                             // Y visible + stage0 drained
#pragma unroll
  for (int ks = 0; ks < 8; ++ks) {
    if (ks < 7) STAGE(ks + 1, (ks + 1) & 1);   // prefetch overlaps compute
    const float* sp = (const float*)(U + STGo) + (ks & 1) * 6144;
    const u16* yb = U + (mw * 16 + ln) * 264 + ks * 32 + q8;
    short8 yh8 = *(const short8*)yb;
    short8 yl8 = *(const short8*)(yb + YLO);
#pragma unroll
    for (int cc = 0; cc < 6; ++cc) {
      int xrow = half * 96 + cc * 16 + ln;
      int xr7  = xrow & 7;
      int c0   = quad * 2;
      float4 f0 = *(const float4*)(sp + xrow * 32 + ((c0 ^ xr7) << 2));
      float4 f1 = *(const float4*)(sp + xrow * 32 + (((c0 + 1) ^ xr7) << 2));
      short8 xbh, xbl;
      cvt8(f0, f1, xbh, xbl);
      accP[cc] = __builtin_amdgcn_mfma_f32_16x16x32_bf16(yh8, xbh, accP[cc], 0, 0, 0);
      accP[cc] = __builtin_amdgcn_mfma_f32_16x16x32_bf16(yh8, xbl, accP[cc], 0, 0, 0);
      accP[cc] = __builtin_amdgcn_mfma_f32_16x16x32_bf16(yl8, xbh, accP[cc], 0, 0, 0);
    }
    __syncthreads();                           // staged(ks+1) ready; reads done
  }

  // ---------------- Softmax in registers ----------------
  int  c_of[6];
  bool vj[6];
#pragma unroll
  for (int cc = 0; cc < 6; ++cc) {
    c_of[cc] = half * 96 + cc * 16 + ln;
    int j = i0 + c_of[cc] - 64;
    vj[cc] = (j >= 0) && (j < NU);
  }
#pragma unroll
  for (int r = 0; r < 4; ++r) {
    int row = mw * 16 + quad * 4 + r;
    float mx = -3.4e38f;
#pragma unroll
    for (int cc = 0; cc < 6; ++cc) {
      int rel = c_of[cc] - row;
      bool inb = (rel >= 0) && (rel < 128);
      if (inb) mx = fmaxf(mx, vj[cc] ? accP[cc][r] : 0.f);
    }
#pragma unroll
    for (int o = 1; o < 16; o <<= 1) mx = fmaxf(mx, __shfl_xor(mx, o));
    if (ln == 0) prt[row][half] = mx;
  }
  __syncthreads();
#pragma unroll
  for (int r = 0; r < 4; ++r) {
    int row = mw * 16 + quad * 4 + r;
    float gm = fmaxf(prt[row][0], prt[row][1]);
    float s = 0.f;
#pragma unroll
    for (int cc = 0; cc < 6; ++cc) {
      int rel = c_of[cc] - row;
      bool inb = (rel >= 0) && (rel < 128);
      float vv = vj[cc] ? accP[cc][r] : 0.f;
      float e  = inb ? __expf(vv - gm) : 0.f;
      s += e;                                      // padded-slot denominator
      accP[cc][r] = (inb && vj[cc]) ? e : 0.f;     // masked numerator
    }
#pragma unroll
    for (int o = 1; o < 16; o <<= 1) s += __shfl_xor(s, o);
    if (ln == 0) prs[row][half] = s;
  }
  __syncthreads();                             // also: all Y/stage reads done
#pragma unroll
  for (int r = 0; r < 4; ++r) {
    int row = mw * 16 + quad * 4 + r;
    float inv = 1.f / (prs[row][0] + prs[row][1]);
#pragma unroll
    for (int cc = 0; cc < 6; ++cc)
      U[row * AMS + c_of[cc]] = bfrn(accP[cc][r] * inv);   // Am overlays dead Y
  }
  __syncthreads();

  // ---------------- build same-mask image Ac1 (overlays dead Y-lo) ----------------
  {
    const int arow = t >> 3, aseg = t & 7;     // 64 rows x 8 col-groups of 24
    const int sr = spkw[arow + 64];
    const int cb = aseg * 24;
#pragma unroll
    for (int p = 0; p < 6; ++p) {
      ushort4 av = *(const ushort4*)(U + arow * AMS + cb + p * 4);
      u16 aq[4] = {av.x, av.y, av.z, av.w};
      u16 b1v[4];
#pragma unroll
      for (int q = 0; q < 4; ++q) {
        int c = cb + p * 4 + q;
        b1v[q] = (spkw[c] == sr) ? aq[q] : (u16)0;
      }
      *(ushort4*)(U + AC1o + arow * AMS + cb + p * 4) = *(const ushort4*)b1v;
    }
  }
  __syncthreads();

  // ---------------- Phase 2: aggregation (barrier-free, band-trick) ----------------
  floatx4 acc2[4][2];
#pragma unroll
  for (int m = 0; m < 4; ++m)
#pragma unroll
    for (int nt = 0; nt < 2; ++nt) acc2[m][nt] = (floatx4){0.f, 0.f, 0.f, 0.f};

#pragma unroll
  for (int kj = 0; kj < 6; ++kj) {             // 192 window slots
    short8 af[4], af1[4];
#pragma unroll
    for (int m = 0; m < 4; ++m) {
      af[m]  = *(const short8*)(U + (m * 16 + ln) * AMS + kj * 32 + q8);
      af1[m] = *(const short8*)(U + AC1o + (m * 16 + ln) * AMS + kj * 32 + q8);
    }
    size_t sb[2];
#pragma unroll
    for (int nt = 0; nt < 2; ++nt)
      sb[nt] = (size_t)ST0 + (size_t)(n0 + nt * 16 + ln) * STROW
             + (size_t)(i0 + kj * 32) + q8;    // +64 guard cancels -64 window
#pragma unroll
    for (int nt = 0; nt < 2; ++nt) {
      short8 b2 = *(const short8*)(ws + sb[nt] + 2 * (size_t)STMAT);  // full
      short8 b1 = *(const short8*)(ws + sb[nt] + 1 * (size_t)STMAT);  // same
#pragma unroll
      for (int m = 0; m < 4; ++m) {
        acc2[m][nt] = __builtin_amdgcn_mfma_f32_16x16x32_bf16(af[m],  b2, acc2[m][nt], 0, 0, 0);
        acc2[m][nt] = __builtin_amdgcn_mfma_f32_16x16x32_bf16(af1[m], b1, acc2[m][nt], 0, 0, 0);
      }
    }
    if (kj >= 2) {                              // pred: band structure
      short8 a0m[4];
#pragma unroll
      for (int m = 0; m < 4; ++m) {
        a0m[m] = af[m];
        if (!(32 * kj >= 16 * m + 79)) {        // partial frag: per-lane mask
          int tthr = m * 16 + ln + 64 - kj * 32 - q8;
#pragma unroll
          for (int e = 0; e < 8; ++e)
            if (e < tthr) a0m[m][e] = 0;
        }
      }
#pragma unroll
      for (int nt = 0; nt < 2; ++nt) {
        short8 b0 = *(const short8*)(ws + sb[nt]);
#pragma unroll
        for (int m = 0; m < 4; ++m) {
          if (32 * kj < 16 * m + 33) continue;  // all-drop (compile-time)
          acc2[m][nt] = __builtin_amdgcn_mfma_f32_16x16x32_bf16(a0m[m], b0, acc2[m][nt], 0, 0, 0);
        }
      }
    }
  }

  // ---------------- log_softmax over 256 dims (8 waves) ----------------
#pragma unroll
  for (int m = 0; m < 4; ++m)
#pragma unroll
    for (int r = 0; r < 4; ++r) {
      float v = fmaxf(acc2[m][0][r], acc2[m][1][r]);
#pragma unroll
      for (int o = 1; o < 16; o <<= 1) v = fmaxf(v, __shfl_xor(v, o));
      if (ln == 0) red[m * 16 + quad * 4 + r][w] = v;
    }
  __syncthreads();
  float gmx[4][4];
#pragma unroll
  for (int m = 0; m < 4; ++m)
#pragma unroll
    for (int r = 0; r < 4; ++r) {
      int row = m * 16 + quad * 4 + r;
      float g = red[row][0];
#pragma unroll
      for (int ww = 1; ww < 8; ++ww) g = fmaxf(g, red[row][ww]);
      gmx[m][r] = g;
    }
  __syncthreads();
#pragma unroll
  for (int m = 0; m < 4; ++m)
#pragma unroll
    for (int r = 0; r < 4; ++r) {
      float e = __expf(acc2[m][0][r] - gmx[m][r]) + __expf(acc2[m][1][r] - gmx[m][r]);
#pragma unroll
      for (int o = 1; o < 16; o <<= 1) e += __shfl_xor(e, o);
      if (ln == 0) red[m * 16 + quad * 4 + r][w] = e;
    }
  __syncthreads();
#pragma unroll
  for (int m = 0; m < 4; ++m)
#pragma unroll
    for (int r = 0; r < 4; ++r) {
      int row = m * 16 + quad * 4 + r;
      float s = red[row][0];
#pragma unroll
      for (int ww = 1; ww < 8; ++ww) s += red[row][ww];
      float lse = gmx[m][r] + logf(s);
      size_t rowg = (size_t)(i0 + row) * DIM;
      out[rowg + n0 + ln]      = acc2[m][0][r] - lse;
      out[rowg + n0 + 16 + ln] = acc2[m][1][r] - lse;
    }
}

extern "C" void kernel_launch(void* const* d_in, const int* in_sizes, int n_in,
                              void* d_out, int out_size, void* d_ws, size_t ws_size,
                              hipStream_t stream) {
  const float* x   = (const float*)d_in[0];
  const int*   spk = (const int*)d_in[1];
  const float* wat = (const float*)d_in[2];
  const float* wpr = (const float*)d_in[3];
  const float* wsu = (const float*)d_in[4];
  const float* wsm = (const float*)d_in[5];
  const float* wdf = (const float*)d_in[6];
  float* out = (float*)d_out;
  u16* ws = (u16*)d_ws;

  hipLaunchKernelGGL(prep, dim3(128), dim3(256), 0, stream,
                     wat, wpr, wsu, wsm, wdf, ws);
  hipLaunchKernelGGL(gemmS1, dim3(512), dim3(512), 0, stream, x, ws);
  hipLaunchKernelGGL(fused_attn, dim3(256), dim3(512), 0, stream, x, ws, spk, out);
}

// Round 15
// 141.758 us; speedup vs baseline: 1.0357x; 1.0357x over previous
//
#include <hip/hip_runtime.h>
#include <hip/hip_bf16.h>

typedef unsigned short u16;
typedef unsigned int u32;
typedef __attribute__((ext_vector_type(8))) short short8;
typedef __attribute__((ext_vector_type(4))) float floatx4;

#define NU 16384
#define DIM 256
#define AMS 200               // Am / Ac1 LDS row stride (u16)
#define AC1o 12800u           // Ac1 (same-mask image) offset in U (64*200)
#define YLO 16896u            // strip/Y lo half offset (hi at 0)
#define STGo 33792u           // ph1 staging dbuf (2 x 12288)

// ws layout (u16 offsets)
#define XHo 0u
#define XLo 4194304u
#define XRo 8388608u
#define ST0 20971520u
#define STROW 16512u          // 64 guard + 16384 + 64 guard
#define STMAT 4227072u        // 256 * STROW
#define WH0o 33652736u        // ST0 + 3*STMAT
#define WL0o 33718272u
#define WRo  33783808u        // 3 mats x 65536

__device__ __forceinline__ u16 bfh(float v) {            // truncate to bf16
  return (u16)(__float_as_uint(v) >> 16);
}
__device__ __forceinline__ float bup(u16 u) {
  return __uint_as_float(((u32)u) << 16);
}
__device__ __forceinline__ u16 bfrn(float v) {           // round-nearest-even
  u32 u = __float_as_uint(v);
  return (u16)((u + 0x7fffu + ((u >> 16) & 1u)) >> 16);
}

// async global->LDS 16B (linear wave dest: base + lane*16)
__device__ __forceinline__ void gload16(const u16* g, u16* l) {
  __builtin_amdgcn_global_load_lds(
      (__attribute__((address_space(1))) void*)(uintptr_t)g,
      (__attribute__((address_space(3))) void*)(uintptr_t)l, 16, 0, 0);
}

// ---------------------------------------------------------------------------
// prep: merged xprep + wpgz.
// ---------------------------------------------------------------------------
__global__ __launch_bounds__(256) void prep(
    const float* __restrict__ x,
    const float* __restrict__ wat, const float* __restrict__ wpr,
    const float* __restrict__ wsu, const float* __restrict__ wsm,
    const float* __restrict__ wdf, u16* __restrict__ ws) {
  const int b = blockIdx.x, t = threadIdx.x;
  if (b < 2048) {
    int idx = (b * 256 + t) * 8;
    float4 v0 = *(const float4*)(x + idx);
    float4 v1 = *(const float4*)(x + idx + 4);
    float a[8] = {v0.x, v0.y, v0.z, v0.w, v1.x, v1.y, v1.z, v1.w};
    u16 h[8], l[8], r[8];
#pragma unroll
    for (int q = 0; q < 8; ++q) {
      h[q] = bfh(a[q]);
      l[q] = bfh(a[q] - bup(h[q]));
      r[q] = bfrn(a[q]);
    }
    *(uint4*)(ws + XHo + idx) = *(const uint4*)h;
    *(uint4*)(ws + XLo + idx) = *(const uint4*)l;
    *(uint4*)(ws + XRo + idx) = *(const uint4*)r;
    return;
  }
  const int b2 = b - 2048;
  if (b2 < 32) {
    const int s = b2 & 7, mat = b2 >> 3, n = t;
    const float* Wa = (mat == 0) ? wat : (mat == 1) ? wpr : (mat == 2) ? wsm : wsu;
    const float* Wb = (mat == 0) ? wat : (mat == 1) ? wsu : (mat == 2) ? wdf : wdf;
    const float c1  = (mat == 0) ? 0.f : (mat == 3) ? 1.f : -1.f;
    u16 hbuf[32], lbuf[32];
#pragma unroll 8
    for (int k = 0; k < 32; ++k) {
      float v = Wa[(s * 32 + k) * 256 + n] + c1 * Wb[(s * 32 + k) * 256 + n];
      if (mat == 0) { hbuf[k] = bfh(v); lbuf[k] = bfh(v - bup(hbuf[k])); }
      else          { hbuf[k] = bfrn(v); }
    }
    u16* dh = ws + ((mat == 0) ? WH0o : (WRo + (size_t)(mat - 1) * 65536))
               + (size_t)s * 8192 + n * 32;
#pragma unroll
    for (int p = 0; p < 4; ++p) *(uint4*)(dh + p * 8) = ((const uint4*)hbuf)[p];
    if (mat == 0) {
      u16* dl = ws + WL0o + (size_t)s * 8192 + n * 32;
#pragma unroll
      for (int p = 0; p < 4; ++p) *(uint4*)(dl + p * 8) = ((const uint4*)lbuf)[p];
    }
  } else {
    int g = (b2 - 32) * 256 + t;                   // 24576 threads
    int r = g >> 13, rem = g & 8191;
    int d = rem >> 5, p = rem & 31;
    size_t base = ST0 + (size_t)r * STMAT + (size_t)d * STROW;
    size_t off = (p < 16) ? (base + p * 4) : (base + 16448 + (p - 16) * 4);
    *(ushort4*)(ws + off) = make_ushort4(0, 0, 0, 0);
  }
}

// ---------------------------------------------------------------------------
// gemmS1: S1..S3 -> S^T.
// ---------------------------------------------------------------------------
__global__ __launch_bounds__(512, 4) void gemmS1(u16* __restrict__ ws) {
  __shared__ __align__(16) u16 U[39168];   // Ar[32*264] @0 ; Ct[3][10240] @8448

  const int t = threadIdx.x, row0 = blockIdx.x * 32;
  const int w = t >> 6, ln = t & 15, quad = (t & 63) >> 4, q8 = quad * 8;
  const int n0 = w * 32;

#pragma unroll
  for (int cc = 0; cc < 2; ++cc) {
    int idx = t + 512 * cc;                  // 0..1023
    int row = idx >> 5, c8 = (idx & 31) * 8;
    *(uint4*)(U + row * 264 + c8) =
        *(const uint4*)(ws + XRo + (size_t)(row0 + row) * 256 + c8);
  }
  __syncthreads();

  floatx4 acc[3][2][2];
#pragma unroll
  for (int mat = 0; mat < 3; ++mat)
#pragma unroll
    for (int m = 0; m < 2; ++m)
#pragma unroll
      for (int nt = 0; nt < 2; ++nt) acc[mat][m][nt] = (floatx4){0.f, 0.f, 0.f, 0.f};

  for (int s = 0; s < 8; ++s) {
    short8 ah[2];
#pragma unroll
    for (int m = 0; m < 2; ++m)
      ah[m] = *(const short8*)(U + (m * 16 + ln) * 264 + s * 32 + q8);
#pragma unroll
    for (int mat = 0; mat < 3; ++mat) {
      short8 bh[2];
#pragma unroll
      for (int nt = 0; nt < 2; ++nt)
        bh[nt] = *(const short8*)(ws + WRo + (size_t)mat * 65536
                                  + (size_t)s * 8192 + (n0 + nt * 16 + ln) * 32 + q8);
#pragma unroll
      for (int m = 0; m < 2; ++m)
#pragma unroll
        for (int nt = 0; nt < 2; ++nt)
          acc[mat][m][nt] = __builtin_amdgcn_mfma_f32_16x16x32_bf16(ah[m], bh[nt], acc[mat][m][nt], 0, 0, 0);
    }
  }

#pragma unroll
  for (int mat = 0; mat < 3; ++mat)
#pragma unroll
    for (int m = 0; m < 2; ++m)
#pragma unroll
      for (int nt = 0; nt < 2; ++nt) {
        int col = n0 + nt * 16 + ln;
        ushort4 pk = make_ushort4(bfrn(acc[mat][m][nt][0]), bfrn(acc[mat][m][nt][1]),
                                  bfrn(acc[mat][m][nt][2]), bfrn(acc[mat][m][nt][3]));
        *(ushort4*)(U + 8448 + mat * 10240 + col * 40 + m * 16 + quad * 4) = pk;
      }
  __syncthreads();

#pragma unroll
  for (int mat = 0; mat < 3; ++mat)
#pragma unroll
    for (int cc = 0; cc < 2; ++cc) {
      int c = t + 512 * cc;                  // 0..1023 : 256 d x 4 parts
      int d = c >> 2, part = c & 3;
      *(uint4*)(ws + ST0 + (size_t)mat * STMAT + (size_t)d * STROW + 64 + row0 + part * 8) =
          *(const uint4*)(U + 8448 + mat * 10240 + d * 40 + part * 8);
    }
}

// ---------------------------------------------------------------------------
// fused_attn (round-7/round-13 measured-best, 144.09us total):
//  Phase A: Y = Xstrip@W_att (split 3-MFMA), strip staged once, Y -> LDS.
//  ph1: double-buffered global_load_lds staging (swizzled), plain
//       __syncthreads per k-step.
//  softmax in registers; Am@0 + Ac1@12800 overlay dead Y.
//  ph2: barrier-free band-trick (rel2=Am, rel1=Ac1, rel0=compile-time band
//       skip/partial mask), direct-global S^T B-frags.
// ---------------------------------------------------------------------------
__global__ __launch_bounds__(512) void fused_attn(
    const u16* __restrict__ ws, const int* __restrict__ spk,
    float* __restrict__ out)
{
  __shared__ __align__(16) u16 U[58368];   // strip/Y hi@0 lo@16896; stage@33792; Am@0 Ac1@12800 after
  __shared__ int spkw[192];
  __shared__ float prt[64][2], prs[64][2];
  __shared__ float red[64][8];

  const int t    = threadIdx.x;
  const int w    = t >> 6;
  const int ln   = t & 15;
  const int quad = (t & 63) >> 4;
  const int q8   = quad * 8;
  // XCD-chunked bijective swizzle (grid 256 % 8 == 0)
  const int bswz = (blockIdx.x & 7) * 32 + (blockIdx.x >> 3);
  const int i0   = bswz * 64;
  const int mw   = w & 3;                      // ph1 m-frag (16 rows)
  const int half = w >> 2;                     // ph1 window col half (96 each)
  const int n0   = w * 32;                     // phase A / ph2 col block

  if (t < 192) spkw[t] = spk[min(max(i0 - 64 + t, 0), NU - 1)];

  // ---------------- Phase A: Y = Xstrip @ W_att ----------------
  {
#pragma unroll
    for (int cc = 0; cc < 8; ++cc) {
      int idx = t + 512 * cc;                  // 0..4095
      int buf = idx >> 11, e = idx & 2047;
      int row = e >> 5, c8 = (e & 31) * 8;
      *(uint4*)(U + buf * YLO + row * 264 + c8) =
          *(const uint4*)(ws + (buf ? XLo : XHo) + (size_t)(i0 + row) * 256 + c8);
    }
    __syncthreads();

    floatx4 acc[4][2];
#pragma unroll
    for (int m = 0; m < 4; ++m)
#pragma unroll
      for (int nt = 0; nt < 2; ++nt) acc[m][nt] = (floatx4){0.f, 0.f, 0.f, 0.f};

    for (int s = 0; s < 8; ++s) {
      short8 ah[4], al[4];
#pragma unroll
      for (int m = 0; m < 4; ++m) {
        ah[m] = *(const short8*)(U + (m * 16 + ln) * 264 + s * 32 + q8);
        al[m] = *(const short8*)(U + YLO + (m * 16 + ln) * 264 + s * 32 + q8);
      }
      short8 bh[2], bl[2];
#pragma unroll
      for (int nt = 0; nt < 2; ++nt) {
        size_t off = (size_t)s * 8192 + (n0 + nt * 16 + ln) * 32 + q8;
        bh[nt] = *(const short8*)(ws + WH0o + off);
        bl[nt] = *(const short8*)(ws + WL0o + off);
      }
#pragma unroll
      for (int m = 0; m < 4; ++m)
#pragma unroll
        for (int nt = 0; nt < 2; ++nt) {
          acc[m][nt] = __builtin_amdgcn_mfma_f32_16x16x32_bf16(ah[m], bh[nt], acc[m][nt], 0, 0, 0);
          acc[m][nt] = __builtin_amdgcn_mfma_f32_16x16x32_bf16(ah[m], bl[nt], acc[m][nt], 0, 0, 0);
          acc[m][nt] = __builtin_amdgcn_mfma_f32_16x16x32_bf16(al[m], bh[nt], acc[m][nt], 0, 0, 0);
        }
    }
    __syncthreads();                           // strip reads complete

    // overwrite strip region with Y hi/lo [64][264]
#pragma unroll
    for (int m = 0; m < 4; ++m)
#pragma unroll
      for (int nt = 0; nt < 2; ++nt) {
        int col = n0 + nt * 16 + ln;
#pragma unroll
        for (int r = 0; r < 4; ++r) {
          int row = m * 16 + quad * 4 + r;
          float y = acc[m][nt][r];
          u16 hh = bfh(y);
          U[row * 264 + col] = hh;
          U[YLO + row * 264 + col] = bfh(y - bup(hh));
        }
      }
  }

  // ---- ph1 staging: async 16B, linear LDS dest, slot-swizzled source ----
  auto STAGE = [&](int ks, int par) {
    const int kd = ks * 32;
    u16* db = U + STGo + par * 12288;
#pragma unroll
    for (int cc = 0; cc < 3; ++cc) {
      int idx  = t + 512 * cc;                 // 0..1535
      int bsel = (idx >= 768) ? 1 : 0;         // 0=hi 1=lo (wave-aligned split)
      int e    = idx - bsel * 768;
      int row  = e >> 2, s = e & 3;
      int sw   = s ^ ((row >> 1) & 3);
      int jc   = min(max(i0 + row - 64, 0), NU - 1);
      const u16* src = ws + (bsel ? XLo : XHo) + (size_t)jc * 256 + kd + sw * 8;
      u16* dst = db + bsel * 6144 + e * 8;
      gload16(src, dst);
    }
  };

  // ---------------- Phase 1: P = Y . Xwin^T ----------------
  floatx4 accP[6];
#pragma unroll
  for (int cc = 0; cc < 6; ++cc) accP[cc] = (floatx4){0.f, 0.f, 0.f, 0.f};

  STAGE(0, 0);
  __syncthreads();                             // Y visible + stage0 drained
#pragma unroll
  for (int ks = 0; ks < 8; ++ks) {
    if (ks < 7) STAGE(ks + 1, (ks + 1) & 1);   // prefetch overlaps compute
    const u16* sp = U + STGo + (ks & 1) * 12288;
    const u16* yb = U + (mw * 16 + ln) * 264 + ks * 32 + q8;
    short8 yh8 = *(const short8*)yb;
    short8 yl8 = *(const short8*)(yb + YLO);
#pragma unroll
    for (int cc = 0; cc < 6; ++cc) {
      int xrow = half * 96 + cc * 16 + ln;
      int slot = quad ^ ((xrow >> 1) & 3);
      const u16* xb = sp + xrow * 32 + slot * 8;
      short8 xbh = *(const short8*)xb;
      short8 xbl = *(const short8*)(xb + 6144);
      accP[cc] = __builtin_amdgcn_mfma_f32_16x16x32_bf16(yh8, xbh, accP[cc], 0, 0, 0);
      accP[cc] = __builtin_amdgcn_mfma_f32_16x16x32_bf16(yh8, xbl, accP[cc], 0, 0, 0);
      accP[cc] = __builtin_amdgcn_mfma_f32_16x16x32_bf16(yl8, xbh, accP[cc], 0, 0, 0);
    }
    __syncthreads();                           // staged(ks+1) ready; reads done
  }

  // ---------------- Softmax in registers ----------------
  int  c_of[6];
  bool vj[6];
#pragma unroll
  for (int cc = 0; cc < 6; ++cc) {
    c_of[cc] = half * 96 + cc * 16 + ln;
    int j = i0 + c_of[cc] - 64;
    vj[cc] = (j >= 0) && (j < NU);
  }
#pragma unroll
  for (int r = 0; r < 4; ++r) {
    int row = mw * 16 + quad * 4 + r;
    float mx = -3.4e38f;
#pragma unroll
    for (int cc = 0; cc < 6; ++cc) {
      int rel = c_of[cc] - row;
      bool inb = (rel >= 0) && (rel < 128);
      if (inb) mx = fmaxf(mx, vj[cc] ? accP[cc][r] : 0.f);
    }
#pragma unroll
    for (int o = 1; o < 16; o <<= 1) mx = fmaxf(mx, __shfl_xor(mx, o));
    if (ln == 0) prt[row][half] = mx;
  }
  __syncthreads();
#pragma unroll
  for (int r = 0; r < 4; ++r) {
    int row = mw * 16 + quad * 4 + r;
    float gm = fmaxf(prt[row][0], prt[row][1]);
    float s = 0.f;
#pragma unroll
    for (int cc = 0; cc < 6; ++cc) {
      int rel = c_of[cc] - row;
      bool inb = (rel >= 0) && (rel < 128);
      float vv = vj[cc] ? accP[cc][r] : 0.f;
      float e  = inb ? __expf(vv - gm) : 0.f;
      s += e;                                      // padded-slot denominator
      accP[cc][r] = (inb && vj[cc]) ? e : 0.f;     // masked numerator
    }
#pragma unroll
    for (int o = 1; o < 16; o <<= 1) s += __shfl_xor(s, o);
    if (ln == 0) prs[row][half] = s;
  }
  __syncthreads();                             // also: all Y/stage reads done
#pragma unroll
  for (int r = 0; r < 4; ++r) {
    int row = mw * 16 + quad * 4 + r;
    float inv = 1.f / (prs[row][0] + prs[row][1]);
#pragma unroll
    for (int cc = 0; cc < 6; ++cc)
      U[row * AMS + c_of[cc]] = bfrn(accP[cc][r] * inv);   // Am overlays dead Y
  }
  __syncthreads();

  // ---------------- build same-mask image Ac1 (overlays dead Y-lo) ----------------
  {
    const int arow = t >> 3, aseg = t & 7;     // 64 rows x 8 col-groups of 24
    const int sr = spkw[arow + 64];
    const int cb = aseg * 24;
#pragma unroll
    for (int p = 0; p < 6; ++p) {
      ushort4 av = *(const ushort4*)(U + arow * AMS + cb + p * 4);
      u16 aq[4] = {av.x, av.y, av.z, av.w};
      u16 b1v[4];
#pragma unroll
      for (int q = 0; q < 4; ++q) {
        int c = cb + p * 4 + q;
        b1v[q] = (spkw[c] == sr) ? aq[q] : (u16)0;
      }
      *(ushort4*)(U + AC1o + arow * AMS + cb + p * 4) = *(const ushort4*)b1v;
    }
  }
  __syncthreads();

  // ---------------- Phase 2: aggregation (barrier-free, band-trick) ----------------
  floatx4 acc2[4][2];
#pragma unroll
  for (int m = 0; m < 4; ++m)
#pragma unroll
    for (int nt = 0; nt < 2; ++nt) acc2[m][nt] = (floatx4){0.f, 0.f, 0.f, 0.f};

#pragma unroll
  for (int kj = 0; kj < 6; ++kj) {             // 192 window slots
    short8 af[4], af1[4];
#pragma unroll
    for (int m = 0; m < 4; ++m) {
      af[m]  = *(const short8*)(U + (m * 16 + ln) * AMS + kj * 32 + q8);
      af1[m] = *(const short8*)(U + AC1o + (m * 16 + ln) * AMS + kj * 32 + q8);
    }
    size_t sb[2];
#pragma unroll
    for (int nt = 0; nt < 2; ++nt)
      sb[nt] = (size_t)ST0 + (size_t)(n0 + nt * 16 + ln) * STROW
             + (size_t)(i0 + kj * 32) + q8;    // +64 guard cancels -64 window
#pragma unroll
    for (int nt = 0; nt < 2; ++nt) {
      short8 b2 = *(const short8*)(ws + sb[nt] + 2 * (size_t)STMAT);  // full
      short8 b1 = *(const short8*)(ws + sb[nt] + 1 * (size_t)STMAT);  // same
#pragma unroll
      for (int m = 0; m < 4; ++m) {
        acc2[m][nt] = __builtin_amdgcn_mfma_f32_16x16x32_bf16(af[m],  b2, acc2[m][nt], 0, 0, 0);
        acc2[m][nt] = __builtin_amdgcn_mfma_f32_16x16x32_bf16(af1[m], b1, acc2[m][nt], 0, 0, 0);
      }
    }
    if (kj >= 2) {                              // pred: band structure
      short8 a0m[4];
#pragma unroll
      for (int m = 0; m < 4; ++m) {
        a0m[m] = af[m];
        if (!(32 * kj >= 16 * m + 79)) {        // partial frag: per-lane mask
          int tthr = m * 16 + ln + 64 - kj * 32 - q8;
#pragma unroll
          for (int e = 0; e < 8; ++e)
            if (e < tthr) a0m[m][e] = 0;
        }
      }
#pragma unroll
      for (int nt = 0; nt < 2; ++nt) {
        short8 b0 = *(const short8*)(ws + sb[nt]);
#pragma unroll
        for (int m = 0; m < 4; ++m) {
          if (32 * kj < 16 * m + 33) continue;  // all-drop (compile-time)
          acc2[m][nt] = __builtin_amdgcn_mfma_f32_16x16x32_bf16(a0m[m], b0, acc2[m][nt], 0, 0, 0);
        }
      }
    }
  }

  // ---------------- log_softmax over 256 dims (8 waves) ----------------
#pragma unroll
  for (int m = 0; m < 4; ++m)
#pragma unroll
    for (int r = 0; r < 4; ++r) {
      float v = fmaxf(acc2[m][0][r], acc2[m][1][r]);
#pragma unroll
      for (int o = 1; o < 16; o <<= 1) v = fmaxf(v, __shfl_xor(v, o));
      if (ln == 0) red[m * 16 + quad * 4 + r][w] = v;
    }
  __syncthreads();
  float gmx[4][4];
#pragma unroll
  for (int m = 0; m < 4; ++m)
#pragma unroll
    for (int r = 0; r < 4; ++r) {
      int row = m * 16 + quad * 4 + r;
      float g = red[row][0];
#pragma unroll
      for (int ww = 1; ww < 8; ++ww) g = fmaxf(g, red[row][ww]);
      gmx[m][r] = g;
    }
  __syncthreads();
#pragma unroll
  for (int m = 0; m < 4; ++m)
#pragma unroll
    for (int r = 0; r < 4; ++r) {
      float e = __expf(acc2[m][0][r] - gmx[m][r]) + __expf(acc2[m][1][r] - gmx[m][r]);
#pragma unroll
      for (int o = 1; o < 16; o <<= 1) e += __shfl_xor(e, o);
      if (ln == 0) red[m * 16 + quad * 4 + r][w] = e;
    }
  __syncthreads();
#pragma unroll
  for (int m = 0; m < 4; ++m)
#pragma unroll
    for (int r = 0; r < 4; ++r) {
      int row = m * 16 + quad * 4 + r;
      float s = red[row][0];
#pragma unroll
      for (int ww = 1; ww < 8; ++ww) s += red[row][ww];
      float lse = gmx[m][r] + logf(s);
      size_t rowg = (size_t)(i0 + row) * DIM;
      out[rowg + n0 + ln]      = acc2[m][0][r] - lse;
      out[rowg + n0 + 16 + ln] = acc2[m][1][r] - lse;
    }
}

extern "C" void kernel_launch(void* const* d_in, const int* in_sizes, int n_in,
                              void* d_out, int out_size, void* d_ws, size_t ws_size,
                              hipStream_t stream) {
  const float* x   = (const float*)d_in[0];
  const int*   spk = (const int*)d_in[1];
  const float* wat = (const float*)d_in[2];
  const float* wpr = (const float*)d_in[3];
  const float* wsu = (const float*)d_in[4];
  const float* wsm = (const float*)d_in[5];
  const float* wdf = (const float*)d_in[6];
  float* out = (float*)d_out;
  u16* ws = (u16*)d_ws;

  hipLaunchKernelGGL(prep, dim3(2176), dim3(256), 0, stream,
                     x, wat, wpr, wsu, wsm, wdf, ws);
  hipLaunchKernelGGL(gemmS1, dim3(512), dim3(512), 0, stream, ws);
  hipLaunchKernelGGL(fused_attn, dim3(256), dim3(512), 0, stream, ws, spk, out);
}